// Round 2
// baseline (472.484 us; speedup 1.0000x reference)
//
#include <hip/hip_runtime.h>

// SSIM (32,3,512,512) fp32, separable 11x11 Gaussian, sqrt-free rational form.
// v2: streaming-row kernel. Block = 256 threads = 256 cols x 64 output rows.
// Per input row: stage (x1,x2) into an 11-deep LDS row ring (static ds offsets
// via unroll-by-11), horizontal 11-tap conv into an 11-deep REGISTER ring of
// 5 h-signals, vertical 11-tap conv gathers the ring -> SSIM -> local sum.
// Global loads for row t+1 are issued before the barrier publishing row t
// (software-pipelined staging). One atomicAdd per block into d_out.

#define IMG_H 512
#define IMG_W 512
#define N_IMGS 96                   // 32 batch * 3 channels
#define BLK_W 256                   // output cols per block (1 col per lane)
#define STRIPE 64                   // output rows per block
#define HALO 5
#define KW 11
#define IN_COLS (BLK_W + 2*HALO)    // 266
#define NBUF KW                     // 11-deep LDS row ring -> static offsets
#define N_STRIPES (IMG_H / STRIPE)  // 8
#define COLB (IMG_W / BLK_W)        // 2
#define N_BLOCKS (N_IMGS * COLB * N_STRIPES)  // 1536
#define T_MAX 77                    // 7*11 unrolled steps; rows beyond 73 are no-ops
#define TOTAL_PIX (32.0f * 3.0f * 512.0f * 512.0f)

__global__ __launch_bounds__(256, 4) void ssim_main(
    const float* __restrict__ img1, const float* __restrict__ img2,
    const float* __restrict__ window, float* __restrict__ out)
{
    __shared__ float2 buf[NBUF][IN_COLS];   // (x1,x2) row ring, 23.4 KB
    __shared__ float s_red[4];

    const int tid = threadIdx.x;

    // Recover 1D gaussian from the 2D window: g[k] = w[5][k] / sqrt(w[5][5])
    float g[KW];
    {
        const float inv = rsqrtf(window[5*KW + 5]);
        #pragma unroll
        for (int k = 0; k < KW; ++k) g[k] = window[5*KW + k] * inv;
    }

    const int b   = blockIdx.x;
    const int img = b / (COLB * N_STRIPES);
    const int rem = b % (COLB * N_STRIPES);
    const int sy  = rem >> 1;                // 0..7
    const int sx  = rem & 1;                 // 0..1
    const int r0  = sy * STRIPE;
    const int x0  = sx * BLK_W;

    const float* __restrict__ p1 = img1 + (size_t)img * (IMG_H * IMG_W);
    const float* __restrict__ p2 = img2 + (size_t)img * (IMG_H * IMG_W);

    // Per-thread staging columns (fixed across rows)
    const int  gx1   = x0 - HALO + tid;                  // element tid
    const bool c1ok  = (unsigned)gx1 < IMG_W;
    const bool tail  = tid < (IN_COLS - BLK_W);          // threads 0..9 stage 2nd elt
    const int  gx2   = gx1 + BLK_W;                      // element tid+256
    const bool c2ok  = tail && ((unsigned)gx2 < IMG_W);

    // h-value register ring (5 signals x 11 slots)
    float r_h1[KW], r_h2[KW], r_h11[KW], r_h22[KW], r_h12[KW];
    #pragma unroll
    for (int i = 0; i < KW; ++i) {
        r_h1[i] = 0.f; r_h2[i] = 0.f; r_h11[i] = 0.f; r_h22[i] = 0.f; r_h12[i] = 0.f;
    }

    const float C1 = 1e-4f;   // (0.01*1.0)^2
    const float C2 = 9e-4f;   // (0.03*1.0)^2
    float sum = 0.f;

    // Prologue: load row t=0 (gy = r0-5) into staging registers.
    float sa = 0.f, sb = 0.f, sa2 = 0.f, sb2 = 0.f;
    {
        const int gy = r0 - HALO;
        if ((unsigned)gy < IMG_H) {
            const int base = gy * IMG_W;
            if (c1ok) { sa  = p1[base + gx1]; sb  = p2[base + gx1]; }
            if (c2ok) { sa2 = p1[base + gx2]; sb2 = p2[base + gx2]; }
        }
    }

    for (int tb = 0; tb < T_MAX; tb += KW) {
        #pragma unroll
        for (int u = 0; u < KW; ++u) {
            const int t  = tb + u;            // t % 11 == u (tb is a multiple of 11)
            // 1) Publish row t from staging registers into LDS slot u.
            buf[u][tid] = make_float2(sa, sb);
            if (tail) buf[u][tid + BLK_W] = make_float2(sa2, sb2);

            // 2) Issue global loads for row t+1 (latency hidden behind consume).
            {
                const int gy = r0 - HALO + t + 1;
                sa = 0.f; sb = 0.f; sa2 = 0.f; sb2 = 0.f;
                if ((unsigned)gy < IMG_H) {
                    const int base = gy * IMG_W;
                    if (c1ok) { sa  = p1[base + gx1]; sb  = p2[base + gx1]; }
                    if (c2ok) { sa2 = p1[base + gx2]; sb2 = p2[base + gx2]; }
                }
            }

            __syncthreads();   // row t visible to all waves

            // 3) Horizontal 11-tap conv at col x0+tid from LDS slot u.
            float h1 = 0.f, h2 = 0.f, h11 = 0.f, h22 = 0.f, h12 = 0.f;
            #pragma unroll
            for (int k = 0; k < KW; ++k) {
                const float2 v = buf[u][tid + k];
                const float t1 = g[k] * v.x;
                const float t2 = g[k] * v.y;
                h1  += t1;
                h2  += t2;
                h11 += t1 * v.x;
                h22 += t2 * v.y;
                h12 += t1 * v.y;
            }
            r_h1[u] = h1; r_h2[u] = h2; r_h11[u] = h11; r_h22[u] = h22; r_h12[u] = h12;

            // 4) Vertical conv + SSIM when the ring covers output row r0+t-10.
            if (t >= 2*HALO && t < 2*HALO + STRIPE) {
                float mu1 = 0.f, mu2 = 0.f, e11 = 0.f, e22 = 0.f, e12 = 0.f;
                #pragma unroll
                for (int m = 0; m < KW; ++m) {
                    const int slot = (u + 1 + m) % KW;   // static index
                    mu1 += g[m] * r_h1[slot];
                    mu2 += g[m] * r_h2[slot];
                    e11 += g[m] * r_h11[slot];
                    e22 += g[m] * r_h22[slot];
                    e12 += g[m] * r_h12[slot];
                }
                const float mu1s = mu1 * mu1, mu2s = mu2 * mu2, mu12 = mu1 * mu2;
                const float s1  = fmaxf(e11 - mu1s, 0.f);
                const float s2  = fmaxf(e22 - mu2s, 0.f);
                const float s12 = e12 - mu12;
                const float num = (2.f * mu12 + C1) * (2.f * s12 + C2);
                const float den = (mu1s + mu2s + C1) * (s1 + s2 + C2);
                sum += num * __builtin_amdgcn_rcpf(den);
            }
        }
    }

    // Block reduction: wave shuffle -> LDS(4) -> one atomicAdd per block.
    #pragma unroll
    for (int off = 32; off > 0; off >>= 1)
        sum += __shfl_down(sum, off, 64);
    if ((tid & 63) == 0) s_red[tid >> 6] = sum;
    __syncthreads();
    if (tid == 0) {
        const float s = s_red[0] + s_red[1] + s_red[2] + s_red[3];
        atomicAdd(out, s * (1.0f / TOTAL_PIX));
    }
}

extern "C" void kernel_launch(void* const* d_in, const int* in_sizes, int n_in,
                              void* d_out, int out_size, void* d_ws, size_t ws_size,
                              hipStream_t stream) {
    const float* img1   = (const float*)d_in[0];
    const float* img2   = (const float*)d_in[1];
    const float* window = (const float*)d_in[2];
    float* out = (float*)d_out;

    hipMemsetAsync(out, 0, sizeof(float), stream);
    ssim_main<<<N_BLOCKS, 256, 0, stream>>>(img1, img2, window, out);
}